// Round 4
// baseline (295.769 us; speedup 1.0000x reference)
//
#include <hip/hip_runtime.h>

// Problem constants
#define HDIM 64
#define LSEQ 2048
#define BATCH 16
#define LN_EPS 1e-5f
#define D_EPS 1e-6f
#define CHUNK 16
#define NCHUNK 128   // 2048 solve-steps (incl. 1 padded) / 16

// ---------------------------------------------------------------------------
// Kernel 1: preprocessing, lane = token. h = LayerNorm(e + MLP(e)), in-lane.
// Weights accessed with wave-uniform addresses -> scalar loads (s_load), used
// as the SGPR operand of v_fma. No LDS, no cross-lane ops.
// ---------------------------------------------------------------------------
__global__ __launch_bounds__(256, 1) void preprocess_kernel(
    const int* __restrict__ seq, const float* __restrict__ embed,
    const float* __restrict__ W1, const float* __restrict__ b1,
    const float* __restrict__ W2, const float* __restrict__ b2,
    const float* __restrict__ gamma, const float* __restrict__ beta,
    float* __restrict__ h_out, float* __restrict__ invd_out)
{
    const int tok = blockIdx.x * 256 + threadIdx.x;
    const int v = seq[tok];

    float e[64];
    {
        const float4* ep = (const float4*)(embed + v * HDIM);
#pragma unroll
        for (int i = 0; i < 16; ++i) {
            float4 t = ep[i];
            e[4*i+0] = t.x; e[4*i+1] = t.y; e[4*i+2] = t.z; e[4*i+3] = t.w;
        }
    }

    float ff[64];
#pragma unroll
    for (int c = 0; c < 64; ++c) ff[c] = b2[c];

    for (int j0 = 0; j0 < 128; j0 += 8) {   // 16 iterations, body ~1 KFMA
        float h8[8];
#pragma unroll
        for (int jj = 0; jj < 8; ++jj) h8[jj] = b1[j0 + jj];
#pragma unroll
        for (int i = 0; i < 64; ++i) {
            const float ei = e[i];
#pragma unroll
            for (int jj = 0; jj < 8; ++jj)
                h8[jj] = fmaf(ei, W1[i * 128 + j0 + jj], h8[jj]);
        }
#pragma unroll
        for (int jj = 0; jj < 8; ++jj) {
            const float hv = fmaxf(h8[jj], 0.f);
#pragma unroll
            for (int c = 0; c < 64; ++c)
                ff[c] = fmaf(hv, W2[(j0 + jj) * 64 + c], ff[c]);
        }
    }

    // x = e + ff (into e); LN stats in-lane with 4 accumulators
    float s0=0.f,s1=0.f,s2=0.f,s3=0.f, q0=0.f,q1=0.f,q2=0.f,q3=0.f;
#pragma unroll
    for (int i = 0; i < 64; i += 4) {
        e[i+0] += ff[i+0]; e[i+1] += ff[i+1]; e[i+2] += ff[i+2]; e[i+3] += ff[i+3];
        s0 += e[i+0]; s1 += e[i+1]; s2 += e[i+2]; s3 += e[i+3];
        q0 = fmaf(e[i+0], e[i+0], q0); q1 = fmaf(e[i+1], e[i+1], q1);
        q2 = fmaf(e[i+2], e[i+2], q2); q3 = fmaf(e[i+3], e[i+3], q3);
    }
    const float mu   = ((s0+s1)+(s2+s3)) * (1.0f/64.0f);
    const float var  = ((q0+q1)+(q2+q3)) * (1.0f/64.0f) - mu * mu;
    const float rstd = 1.0f / sqrtf(var + LN_EPS);

    float hh = 0.f;
    float* hp = h_out + (size_t)tok * HDIM;
#pragma unroll
    for (int i = 0; i < 64; i += 4) {
        float4 o;
        o.x = (e[i+0] - mu) * rstd * gamma[i+0] + beta[i+0];
        o.y = (e[i+1] - mu) * rstd * gamma[i+1] + beta[i+1];
        o.z = (e[i+2] - mu) * rstd * gamma[i+2] + beta[i+2];
        o.w = (e[i+3] - mu) * rstd * gamma[i+3] + beta[i+3];
        hh = fmaf(o.x, o.x, hh); hh = fmaf(o.y, o.y, hh);
        hh = fmaf(o.z, o.z, hh); hh = fmaf(o.w, o.w, hh);
        *(float4*)(hp + i) = o;
    }
    invd_out[tok] = 1.0f / (hh + D_EPS);
}

// ---------------------------------------------------------------------------
// Kernel 2: Gram precompute. Solve-order indexing: k_sigma = h[2047-sigma]
// (sigma=0 is a padded zero key). For each batch b, chunk c:
//   G[b][c][i][j] = k_{16c+i} . k_{16c+j}   for i>j, else 0   (in-chunk)
//   X[b][c][i][j] = k_{16c+i} . k_{16(c-1)+j}                 (cross-chunk, c>=1)
// Block = (b,c), 256 threads = one (i,j) pair each.
// ---------------------------------------------------------------------------
__global__ __launch_bounds__(256) void gram_kernel(
    const float* __restrict__ h, float* __restrict__ G, float* __restrict__ X)
{
    const int b = blockIdx.x >> 7;
    const int c = blockIdx.x & 127;
    __shared__ float K[32][68];   // +4 dword pad: breaks same-bank row stride

    const float* hb = h + (size_t)b * LSEQ * HDIM;
    const int t0 = 2032 - 16 * c;

#pragma unroll
    for (int s = 0; s < 2; ++s) {
        const int flat = threadIdx.x + 256 * s;   // float4 index, 512 total
        const int row = flat >> 4, col = (flat & 15) * 4;
        const int t = t0 + row;
        float4 val = make_float4(0.f, 0.f, 0.f, 0.f);
        if (t <= 2047 && !(t == 2047 && c == 0))
            val = *(const float4*)(hb + (size_t)t * HDIM + col);
        *(float4*)(&K[row][col]) = val;
    }
    __syncthreads();

    const int i = threadIdx.x >> 4, j = threadIdx.x & 15;
    // chunk c step i  -> staged row 15-i ; chunk c-1 step j -> staged row 31-j
    const float4* A = (const float4*)(&K[15 - i][0]);

    float g = 0.f;
    if (i > j) {
        const float4* Bv = (const float4*)(&K[15 - j][0]);
#pragma unroll
        for (int c4 = 0; c4 < 16; ++c4) {
            float4 a = A[c4], bb = Bv[c4];
            g += a.x*bb.x + a.y*bb.y + a.z*bb.z + a.w*bb.w;
        }
    }
    G[((size_t)(b * NCHUNK + c)) * 256 + threadIdx.x] = g;

    float x = 0.f;
    {
        const float4* Bv = (const float4*)(&K[31 - j][0]);
#pragma unroll
        for (int c4 = 0; c4 < 16; ++c4) {
            float4 a = A[c4], bb = Bv[c4];
            x += a.x*bb.x + a.y*bb.y + a.z*bb.z + a.w*bb.w;
        }
    }
    X[((size_t)(b * NCHUNK + c)) * 256 + threadIdx.x] = x;
}

// ---------------------------------------------------------------------------
// Kernel 3: chunked backward scan. 1 wave per batch, lane = component.
// Per chunk: scalar triangular solve (3 VALU/step, chain ~14 cyc/step) using
// precomputed G; next chunk's P built off-chain from stale r (T1 dots, 2-level
// DPP + LDS transpose) and corrected with cross-Gram X during the epilogue.
// ---------------------------------------------------------------------------
__device__ __forceinline__ float dpp_add_xor1(float x) {
    return x + __int_as_float(__builtin_amdgcn_mov_dpp(__float_as_int(x), 0xB1, 0xF, 0xF, true));
}
__device__ __forceinline__ float dpp_add_xor2(float x) {
    return x + __int_as_float(__builtin_amdgcn_mov_dpp(__float_as_int(x), 0x4E, 0xF, 0xF, true));
}
__device__ __forceinline__ float rdlane(float v, int l) {
    return __int_as_float(__builtin_amdgcn_readlane(__float_as_int(v), l));
}

__global__ __launch_bounds__(64, 1) void scan_kernel(
    const float* __restrict__ h, const float* __restrict__ invd,
    const float* __restrict__ G, const float* __restrict__ X,
    const float* __restrict__ Wr, const float* __restrict__ br,
    const float* __restrict__ Wo, const float* __restrict__ bo,
    float* __restrict__ out)
{
    const int b    = blockIdx.x;
    const int lane = threadIdx.x;     // component index
    const int jj   = lane & 15;       // solve-slot index (replicated x4)

    const float* hb = h + (size_t)b * LSEQ * HDIM;
    const float* db = invd + b * LSEQ;
    const float* Gb = G + (size_t)b * NCHUNK * 256;
    const float* Xb = X + (size_t)b * NCHUNK * 256;

    __shared__ float part[CHUNK * 20];  // 16 dots x 16 quad-partials, stride 20
    __shared__ float cs[64], rs[64];

    float r   = hb[(size_t)2047 * HDIM + lane];   // q
    float ctx = 0.f;

    // LDS transpose addresses (dwords): wval[g] = quad-partial of dot 4g+(lane&3)
    int wa[4];
#pragma unroll
    for (int g = 0; g < 4; ++g) wa[g] = (4 * g + (lane & 3)) * 20 + (lane >> 2);
    const int ra = jj * 20;

    // T1 dots: P_i = Kn[i] . r, result replicated to all lanes' slot jj
    auto t1dots = [&](float (&Kn)[16]) -> float {
        float wval[4];
#pragma unroll
        for (int i = 0; i < 16; ++i) {
            float t = Kn[i] * r;
            t = dpp_add_xor1(t);
            t = dpp_add_xor2(t);           // quad partial (4 comps)
            if ((lane & 3) == (i & 3)) wval[i >> 2] = t;
        }
#pragma unroll
        for (int g = 0; g < 4; ++g) part[wa[g]] = wval[g];
        __syncthreads();
        float4 p0 = *(float4*)&part[ra + 0];
        float4 p1 = *(float4*)&part[ra + 4];
        float4 p2 = *(float4*)&part[ra + 8];
        float4 p3 = *(float4*)&part[ra + 12];
        __syncthreads();
        return (((p0.x+p0.y)+(p0.z+p0.w)) + ((p1.x+p1.y)+(p1.z+p1.w)))
             + (((p2.x+p2.y)+(p2.z+p2.w)) + ((p3.x+p3.y)+(p3.z+p3.w)));
    };

    // ---- prologue: chunk 0 state ----
    float K[16], vG[16], vP, vivd;
#pragma unroll
    for (int j = 0; j < 16; ++j) K[j] = hb[(size_t)(2047 - j) * HDIM + lane];
    K[0] = 0.f;                                   // sigma = 0 padded key
    {
        const float* gp = Gb + jj * 16;
#pragma unroll
        for (int g4 = 0; g4 < 4; ++g4) {
            float4 t = *(const float4*)(gp + g4 * 4);
            vG[4*g4+0] = t.x; vG[4*g4+1] = t.y; vG[4*g4+2] = t.z; vG[4*g4+3] = t.w;
        }
    }
    vivd = db[2047 - jj];
    vP = t1dots(K);                               // P for chunk 0 (P_0 = 0)

    for (int c = 0; c < NCHUNK; ++c) {
        const int cn  = c + 1;
        const int cnc = cn < NCHUNK ? cn : NCHUNK - 1;   // clamp (last iter dead)

        // prefetch next chunk
        float Kn[16], vGn[16], vX[16], vivdn;
#pragma unroll
        for (int j = 0; j < 16; ++j) {
            int t = 2047 - 16 * cn - j;
            if (t < 0) t = 0;
            Kn[j] = hb[(size_t)t * HDIM + lane];
        }
        {
            const float* gp = Gb + (size_t)cnc * 256 + jj * 16;
            const float* xp = Xb + (size_t)cnc * 256 + jj * 16;
#pragma unroll
            for (int g4 = 0; g4 < 4; ++g4) {
                float4 t = *(const float4*)(gp + g4 * 4);
                vGn[4*g4+0] = t.x; vGn[4*g4+1] = t.y; vGn[4*g4+2] = t.z; vGn[4*g4+3] = t.w;
                float4 u = *(const float4*)(xp + g4 * 4);
                vX[4*g4+0] = u.x; vX[4*g4+1] = u.y; vX[4*g4+2] = u.z; vX[4*g4+3] = u.w;
            }
        }
        {
            int idx = 2047 - 16 * cn - jj;
            if (idx < 0) idx = 0;
            vivdn = db[idx];
        }

        // solve chunk c (scalar chain: mul -> readlane -> fma per step)
#pragma unroll
        for (int j = 0; j < 16; ++j) {
            const float s = rdlane(vP * vivd, j);
            vP = fmaf(-s, vG[j], vP);
        }
        const float vD = vP;
        const float vS = vP * vivd;

        // T1 dots for next chunk (uses stale r; latency hidden behind solve)
        float vPn = t1dots(Kn);

        // epilogue: apply chunk c's d/s to ctx, r, and correct vPn via X
#pragma unroll
        for (int j = 0; j < 16; ++j) {
            const float d = rdlane(vD, j);
            const float s = rdlane(vS, j);
            ctx = fmaf(d, K[j], ctx);
            r   = fmaf(-s, K[j], r);
            vPn = fmaf(-s, vX[j], vPn);
        }

        // rotate state
        vP = vPn; vivd = vivdn;
#pragma unroll
        for (int j = 0; j < 16; ++j) { K[j] = Kn[j]; vG[j] = vGn[j]; }
    }

    // ---- output projection: out[b] = (ctx Wr + br) Wo + bo ----
    cs[lane] = ctx;
    __syncthreads();
    float rv = br[lane];
#pragma unroll
    for (int i = 0; i < 64; ++i) rv = fmaf(cs[i], Wr[i * HDIM + lane], rv);
    rs[lane] = rv;
    __syncthreads();
    float ov = bo[lane];
#pragma unroll
    for (int i = 0; i < 64; ++i) ov = fmaf(rs[i], Wo[i * HDIM + lane], ov);
    out[(size_t)b * HDIM + lane] = ov;
}

// ---------------------------------------------------------------------------
extern "C" void kernel_launch(void* const* d_in, const int* in_sizes, int n_in,
                              void* d_out, int out_size, void* d_ws, size_t ws_size,
                              hipStream_t stream)
{
    const int*   seq   = (const int*)  d_in[0];
    const float* embed = (const float*)d_in[1];
    const float* W1    = (const float*)d_in[2];
    const float* b1    = (const float*)d_in[3];
    const float* W2    = (const float*)d_in[4];
    const float* b2    = (const float*)d_in[5];
    const float* gamma = (const float*)d_in[6];
    const float* beta  = (const float*)d_in[7];
    const float* Wr    = (const float*)d_in[8];
    const float* br    = (const float*)d_in[9];
    const float* Wo    = (const float*)d_in[10];
    const float* bo    = (const float*)d_in[11];

    float* h_ws    = (float*)d_ws;                              // 8 MB
    float* invd_ws = h_ws + (size_t)BATCH * LSEQ * HDIM;        // 128 KB
    float* G_ws    = invd_ws + (size_t)BATCH * LSEQ;            // 2 MB
    float* X_ws    = G_ws + (size_t)BATCH * NCHUNK * 256;       // 2 MB
    float* outp    = (float*)d_out;

    hipLaunchKernelGGL(preprocess_kernel, dim3(BATCH * LSEQ / 256), dim3(256), 0, stream,
                       seq, embed, W1, b1, W2, b2, gamma, beta, h_ws, invd_ws);
    hipLaunchKernelGGL(gram_kernel, dim3(BATCH * NCHUNK), dim3(256), 0, stream,
                       h_ws, G_ws, X_ws);
    hipLaunchKernelGGL(scan_kernel, dim3(BATCH), dim3(64), 0, stream,
                       h_ws, invd_ws, G_ws, X_ws, Wr, br, Wo, bo, outp);
}

// Round 5
// 211.068 us; speedup vs baseline: 1.4013x; 1.4013x over previous
//
#include <hip/hip_runtime.h>

// Problem constants
#define HDIM 64
#define LSEQ 2048
#define BATCH 16
#define LN_EPS 1e-5f
#define D_EPS 1e-6f
#define CHUNK 16
#define NCHUNK 128   // 2048 solve slots (incl. 1 zero-padded) / 16
#define NSEG 16
#define CPS 8        // chunks per segment

typedef unsigned short u16;
typedef unsigned int   u32;

__device__ __forceinline__ float bf2f(u16 v) {
    return __uint_as_float(((u32)v) << 16);
}
__device__ __forceinline__ u16 f2bf(float f) {   // round-to-nearest-even
    u32 u = __float_as_uint(f);
    return (u16)((u + 0x7FFFu + ((u >> 16) & 1u)) >> 16);
}

// ---------------------------------------------------------------------------
// Kernel 1: per-token preprocessing (R3 structure; bf16 h output).
//   h = LayerNorm(e + MLP(e)); invd = 1/(h_bf16.h_bf16 + D_EPS)  (invd is
//   computed from the ROUNDED h so the scan's projection is self-consistent)
// ---------------------------------------------------------------------------
__global__ __launch_bounds__(256) void preprocess_kernel(
    const int* __restrict__ seq, const float* __restrict__ embed,
    const float* __restrict__ W1, const float* __restrict__ b1,
    const float* __restrict__ W2, const float* __restrict__ b2,
    const float* __restrict__ gamma, const float* __restrict__ beta,
    u16* __restrict__ h_out, float* __restrict__ invd_out)
{
    __shared__ float sW1[64 * 128];   // 32 KB
    __shared__ float sW2[128 * 64];   // 32 KB
    __shared__ float se[4][64];
    __shared__ float shid[4][128];

    const int tid = threadIdx.x;
    {
        const float4* src1 = (const float4*)W1;
        const float4* src2 = (const float4*)W2;
        float4* dst1 = (float4*)sW1;
        float4* dst2 = (float4*)sW2;
#pragma unroll
        for (int i = 0; i < 8; ++i) {
            dst1[tid + 256 * i] = src1[tid + 256 * i];
            dst2[tid + 256 * i] = src2[tid + 256 * i];
        }
    }
    const int w    = tid >> 6;
    const int lane = tid & 63;
    const float gm  = gamma[lane], bt = beta[lane];
    const float b1a = b1[lane], b1b = b1[lane + 64], b2v = b2[lane];
    __syncthreads();

    for (int it = 0; it < 8; ++it) {
        const int token = blockIdx.x * 32 + w * 8 + it;
        const int v = seq[token];
        const float e = embed[v * HDIM + lane];
        se[w][lane] = e;
        __syncthreads();

        float a0 = b1a, a1 = b1b;
#pragma unroll
        for (int i = 0; i < 64; ++i) {
            const float ei = se[w][i];
            a0 = fmaf(ei, sW1[i * 128 + lane],      a0);
            a1 = fmaf(ei, sW1[i * 128 + 64 + lane], a1);
        }
        a0 = fmaxf(a0, 0.f);
        a1 = fmaxf(a1, 0.f);
        shid[w][lane]      = a0;
        shid[w][lane + 64] = a1;
        __syncthreads();

        float f = b2v;
#pragma unroll
        for (int k = 0; k < 128; ++k)
            f = fmaf(shid[w][k], sW2[k * HDIM + lane], f);

        const float x = e + f;

        float s1 = x, s2 = x * x;
#pragma unroll
        for (int m = 1; m < 64; m <<= 1) {
            s1 += __shfl_xor(s1, m);
            s2 += __shfl_xor(s2, m);
        }
        const float mu  = s1 * (1.0f / 64.0f);
        const float var = s2 * (1.0f / 64.0f) - mu * mu;
        const float hv  = (x - mu) / sqrtf(var + LN_EPS) * gm + bt;

        const u16  hraw = f2bf(hv);
        const float hq  = bf2f(hraw);
        float d = hq * hq;
#pragma unroll
        for (int m = 1; m < 64; m <<= 1) d += __shfl_xor(d, m);

        h_out[(size_t)token * HDIM + lane] = hraw;
        if (lane == 0) invd_out[token] = 1.0f / (d + D_EPS);
    }
}

// ---------------------------------------------------------------------------
// Kernel 2: segment composition. Block = (batch b, segment s); maintains in
// LDS the dense affine action of the segment's 8 chunks:
//   S = A_c7 ... A_c0   (64x64),   V = sum_c U_c * (A_{c-1}...A_c0)
// where per chunk (solve order, k_sigma = h[2047-sigma], sigma=0 padded 0):
//   L B = K  (L unit-lower, L[i][j] = (k_i.k_j)*ivd_j),  Z = B S
//   A_c S = S - K^T (D Z),  U_c S = K^T Z
// Writes packed bf16 (S,V) per (b,s) for the tiny serial final kernel.
// ---------------------------------------------------------------------------
__global__ __launch_bounds__(256, 1) void compose_kernel(
    const u16* __restrict__ hb16, const float* __restrict__ invd,
    u32* __restrict__ PK)
{
    const int b = blockIdx.x >> 4;
    const int s = blockIdx.x & 15;
    const u16*   hbase = hb16 + (size_t)b * LSEQ * HDIM;
    const float* dbase = invd + b * LSEQ;

    __shared__ float S[64][68];
    __shared__ float V[64][68];
    __shared__ float K[16][68];
    __shared__ float Bm[16][68];
    __shared__ float Z[16][68];
    __shared__ float Zt[16][68];
    __shared__ float Gm[16][17];
    __shared__ float ivd_s[16];

    const int t = threadIdx.x;

    // init S = I, V = 0
    for (int idx = t; idx < 64 * 64; idx += 256) {
        const int m = idx >> 6, n = idx & 63;
        S[m][n] = (m == n) ? 1.0f : 0.0f;
        V[m][n] = 0.0f;
    }

    for (int cc = 0; cc < CPS; ++cc) {
        const int c = s * CPS + cc;
        __syncthreads();   // staging vs previous phase-5 reads / init

        // ---- stage K (bf16 -> f32) and ivd ----
        {
            const int j  = t >> 4;
            const int n0 = (t & 15) * 4;
            const int sigma = 16 * c + j;
            float4 kv = make_float4(0.f, 0.f, 0.f, 0.f);
            if (sigma > 0) {
                const ushort4 raw = *(const ushort4*)(hbase + (size_t)(2047 - sigma) * HDIM + n0);
                kv.x = bf2f(raw.x); kv.y = bf2f(raw.y); kv.z = bf2f(raw.z); kv.w = bf2f(raw.w);
            }
            *(float4*)&K[j][n0] = kv;
            if (t < 16) ivd_s[t] = dbase[2047 - (16 * c + t)];
        }
        __syncthreads();

        // ---- Gram: Gm[i][j] = (k_i . k_j) * ivd_j, i > j ----
        {
            const int i = t >> 4, j = t & 15;
            if (i > j) {
                float acc = 0.f;
#pragma unroll
                for (int m = 0; m < 64; m += 4) {
                    const float4 a  = *(const float4*)&K[i][m];
                    const float4 bb = *(const float4*)&K[j][m];
                    acc += a.x * bb.x + a.y * bb.y + a.z * bb.z + a.w * bb.w;
                }
                Gm[i][j] = acc * ivd_s[j];
            }
        }
        __syncthreads();

        // ---- B: forward substitution L B = K (wave 0, B rows in registers) --
        if (t < 64) {
            const int n = t;
            float Breg[16];
#pragma unroll
            for (int i = 0; i < 16; ++i) {
                float acc = K[i][n];
#pragma unroll
                for (int j = 0; j < 16; ++j)
                    if (j < i) acc = fmaf(-Gm[i][j], Breg[j], acc);
                Breg[i] = acc;
                Bm[i][n] = acc;
            }
        }
        __syncthreads();

        // ---- Z = B S ; Zt = D Z ----  thread = (i = t&15, col-quad nb = t>>4)
        {
            const int i  = t & 15;
            const int n0 = (t >> 4) * 4;
            float4 z = make_float4(0.f, 0.f, 0.f, 0.f);
#pragma unroll
            for (int mq = 0; mq < 16; ++mq) {
                const float4 bq = *(const float4*)&Bm[i][mq * 4];
                const float4 s0 = *(const float4*)&S[mq * 4 + 0][n0];
                const float4 s1 = *(const float4*)&S[mq * 4 + 1][n0];
                const float4 s2 = *(const float4*)&S[mq * 4 + 2][n0];
                const float4 s3 = *(const float4*)&S[mq * 4 + 3][n0];
                z.x = fmaf(bq.x, s0.x, fmaf(bq.y, s1.x, fmaf(bq.z, s2.x, fmaf(bq.w, s3.x, z.x))));
                z.y = fmaf(bq.x, s0.y, fmaf(bq.y, s1.y, fmaf(bq.z, s2.y, fmaf(bq.w, s3.y, z.y))));
                z.z = fmaf(bq.x, s0.z, fmaf(bq.y, s1.z, fmaf(bq.z, s2.z, fmaf(bq.w, s3.z, z.z))));
                z.w = fmaf(bq.x, s0.w, fmaf(bq.y, s1.w, fmaf(bq.z, s2.w, fmaf(bq.w, s3.w, z.w))));
            }
            *(float4*)&Z[i][n0] = z;
            const float iv = ivd_s[i];
            float4 zt; zt.x = z.x * iv; zt.y = z.y * iv; zt.z = z.z * iv; zt.w = z.w * iv;
            *(float4*)&Zt[i][n0] = zt;
        }
        __syncthreads();

        // ---- S -= K^T Zt ; V += K^T Z ----
        // thread = (nb = t&15 -> n0, mh = t>>4 -> rows mh+16p)
        {
            const int n0 = (t & 15) * 4;
            const int mh = t >> 4;
            float4 sacc[4], vacc[4];
#pragma unroll
            for (int p = 0; p < 4; ++p) {
                sacc[p] = *(float4*)&S[mh + 16 * p][n0];
                vacc[p] = *(float4*)&V[mh + 16 * p][n0];
            }
#pragma unroll
            for (int j = 0; j < 16; ++j) {
                const float4 zq  = *(const float4*)&Z[j][n0];
                const float4 ztq = *(const float4*)&Zt[j][n0];
                const float k0 = K[j][mh];
                const float k1 = K[j][mh + 16];
                const float k2 = K[j][mh + 32];
                const float k3 = K[j][mh + 48];
                vacc[0].x = fmaf(k0, zq.x, vacc[0].x); vacc[0].y = fmaf(k0, zq.y, vacc[0].y);
                vacc[0].z = fmaf(k0, zq.z, vacc[0].z); vacc[0].w = fmaf(k0, zq.w, vacc[0].w);
                vacc[1].x = fmaf(k1, zq.x, vacc[1].x); vacc[1].y = fmaf(k1, zq.y, vacc[1].y);
                vacc[1].z = fmaf(k1, zq.z, vacc[1].z); vacc[1].w = fmaf(k1, zq.w, vacc[1].w);
                vacc[2].x = fmaf(k2, zq.x, vacc[2].x); vacc[2].y = fmaf(k2, zq.y, vacc[2].y);
                vacc[2].z = fmaf(k2, zq.z, vacc[2].z); vacc[2].w = fmaf(k2, zq.w, vacc[2].w);
                vacc[3].x = fmaf(k3, zq.x, vacc[3].x); vacc[3].y = fmaf(k3, zq.y, vacc[3].y);
                vacc[3].z = fmaf(k3, zq.z, vacc[3].z); vacc[3].w = fmaf(k3, zq.w, vacc[3].w);
                sacc[0].x = fmaf(-k0, ztq.x, sacc[0].x); sacc[0].y = fmaf(-k0, ztq.y, sacc[0].y);
                sacc[0].z = fmaf(-k0, ztq.z, sacc[0].z); sacc[0].w = fmaf(-k0, ztq.w, sacc[0].w);
                sacc[1].x = fmaf(-k1, ztq.x, sacc[1].x); sacc[1].y = fmaf(-k1, ztq.y, sacc[1].y);
                sacc[1].z = fmaf(-k1, ztq.z, sacc[1].z); sacc[1].w = fmaf(-k1, ztq.w, sacc[1].w);
                sacc[2].x = fmaf(-k2, ztq.x, sacc[2].x); sacc[2].y = fmaf(-k2, ztq.y, sacc[2].y);
                sacc[2].z = fmaf(-k2, ztq.z, sacc[2].z); sacc[2].w = fmaf(-k2, ztq.w, sacc[2].w);
                sacc[3].x = fmaf(-k3, ztq.x, sacc[3].x); sacc[3].y = fmaf(-k3, ztq.y, sacc[3].y);
                sacc[3].z = fmaf(-k3, ztq.z, sacc[3].z); sacc[3].w = fmaf(-k3, ztq.w, sacc[3].w);
            }
#pragma unroll
            for (int p = 0; p < 4; ++p) {
                *(float4*)&S[mh + 16 * p][n0] = sacc[p];
                *(float4*)&V[mh + 16 * p][n0] = vacc[p];
            }
        }
    }
    __syncthreads();

    // ---- writeback: pk[j*64+i] = pack(bf16(S[i][j]), bf16(V[i][j])) ----
    u32* pk = PK + ((size_t)(b * NSEG + s) << 12);
    for (int idx = t; idx < 4096; idx += 256) {
        const int j = idx >> 6, i = idx & 63;
        const u32 sb = ((u32)f2bf(S[i][j])) << 16;
        const u32 vb = (u32)f2bf(V[i][j]);
        pk[idx] = sb | vb;
    }
}

// ---------------------------------------------------------------------------
// Kernel 3: serial segment pass + output projection. 16 blocks x 1 wave.
//   r = q; for s: ctx += V_s r; r = S_s r;   out = (ctx Wr + br) Wo + bo
// ---------------------------------------------------------------------------
__global__ __launch_bounds__(64, 1) void final_kernel(
    const u16* __restrict__ hb16, const u32* __restrict__ PK,
    const float* __restrict__ Wr, const float* __restrict__ br,
    const float* __restrict__ Wo, const float* __restrict__ bo,
    float* __restrict__ out)
{
    const int b    = blockIdx.x;
    const int lane = threadIdx.x;

    __shared__ float rl[64];
    __shared__ float cs[64], rs[64];

    float r   = bf2f(hb16[(size_t)b * LSEQ * HDIM + (size_t)2047 * HDIM + lane]);
    float ctx = 0.f;

    for (int s = 0; s < NSEG; ++s) {
        rl[lane] = r;
        __syncthreads();
        const u32* pk = PK + ((size_t)(b * NSEG + s) << 12);
        float accr = 0.f, accc = 0.f;
#pragma unroll 8
        for (int j = 0; j < 64; ++j) {
            const u32 p = pk[j * 64 + lane];
            const float Sv = __uint_as_float(p & 0xFFFF0000u);
            const float Vv = __uint_as_float(p << 16);
            const float rj = rl[j];
            accr = fmaf(Sv, rj, accr);
            accc = fmaf(Vv, rj, accc);
        }
        ctx += accc;
        r = accr;
        __syncthreads();
    }

    cs[lane] = ctx;
    __syncthreads();
    float rv = br[lane];
#pragma unroll
    for (int i = 0; i < 64; ++i) rv = fmaf(cs[i], Wr[i * HDIM + lane], rv);
    rs[lane] = rv;
    __syncthreads();
    float ov = bo[lane];
#pragma unroll
    for (int i = 0; i < 64; ++i) ov = fmaf(rs[i], Wo[i * HDIM + lane], ov);
    out[(size_t)b * HDIM + lane] = ov;
}

// ---------------------------------------------------------------------------
extern "C" void kernel_launch(void* const* d_in, const int* in_sizes, int n_in,
                              void* d_out, int out_size, void* d_ws, size_t ws_size,
                              hipStream_t stream)
{
    const int*   seq   = (const int*)  d_in[0];
    const float* embed = (const float*)d_in[1];
    const float* W1    = (const float*)d_in[2];
    const float* b1    = (const float*)d_in[3];
    const float* W2    = (const float*)d_in[4];
    const float* b2    = (const float*)d_in[5];
    const float* gamma = (const float*)d_in[6];
    const float* beta  = (const float*)d_in[7];
    const float* Wr    = (const float*)d_in[8];
    const float* br    = (const float*)d_in[9];
    const float* Wo    = (const float*)d_in[10];
    const float* bo    = (const float*)d_in[11];

    u16*   h_ws    = (u16*)d_ws;                                   // 4 MB
    float* invd_ws = (float*)(h_ws + (size_t)BATCH * LSEQ * HDIM); // 128 KB
    u32*   pk_ws   = (u32*)(invd_ws + (size_t)BATCH * LSEQ);       // 4 MB
    float* outp    = (float*)d_out;

    hipLaunchKernelGGL(preprocess_kernel, dim3(BATCH * LSEQ / 32), dim3(256), 0, stream,
                       seq, embed, W1, b1, W2, b2, gamma, beta, h_ws, invd_ws);
    hipLaunchKernelGGL(compose_kernel, dim3(BATCH * NSEG), dim3(256), 0, stream,
                       h_ws, invd_ws, pk_ws);
    hipLaunchKernelGGL(final_kernel, dim3(BATCH), dim3(64), 0, stream,
                       h_ws, pk_ws, Wr, br, Wo, bo, outp);
}